// Round 7
// baseline (734.246 us; speedup 1.0000x reference)
//
#include <hip/hip_runtime.h>
#include <hip/hip_bf16.h>

typedef __hip_bfloat16 bf16;
typedef __attribute__((ext_vector_type(8))) short short8;
typedef __attribute__((ext_vector_type(4))) float f32x4;

#define N_PTS 50000
#define N_ROWS (N_PTS * 16)
#define EPS 1e-5f
#define NSH 16   // stat shadow copies

__device__ __forceinline__ float bf2f(bf16 x) { return __bfloat162float(x); }
__device__ __forceinline__ bf16 f2bf(float x) { return __float2bfloat16(x); }
__device__ __forceinline__ float us2f(unsigned short u) {
    union { unsigned int i; float f; } c; c.i = ((unsigned int)u) << 16; return c.f;
}
__device__ __forceinline__ unsigned short f2us(float x) {
    bf16 b = __float2bfloat16(x); return *reinterpret_cast<unsigned short*>(&b);
}

struct PtrTable { const void* p[32]; };
struct IntTable { int v[32]; };

// ---- sniff: f32 (flag=1) vs bf16 (flag=0) ----
__global__ __launch_bounds__(256) void sniff_kernel(const void* feat, int* flag)
{
    __shared__ int cnt;
    if (threadIdx.x == 0) cnt = 0;
    __syncthreads();
    const unsigned short* u = (const unsigned short*)feat;
    int local = 0;
    #pragma unroll
    for (int j = 0; j < 8; ++j) {
        unsigned short bits = u[2 * (threadIdx.x * 8 + j)];
        int e = (bits >> 7) & 0xFF;
        if (e >= 140) local++;
    }
    atomicAdd(&cnt, local);
    __syncthreads();
    if (threadIdx.x == 0) *flag = (cnt > 16) ? 1 : 0;
}

// ---- canon: vectorized copy to canonical bf16 + coordf4 ----
__global__ __launch_bounds__(256) void canon_kernel(
    const int* __restrict__ flag, PtrTable pt, IntTable sz, IntTable off,
    bf16* __restrict__ dst, float4* __restrict__ coordf4)
{
    const bool isf32 = (*flag != 0);
    const int stride = gridDim.x * blockDim.x;
    const int tid0 = blockIdx.x * blockDim.x + threadIdx.x;
    for (int s = 0; s < 32; ++s) {
        const int n4 = sz.v[s] >> 2;
        ushort4* d4 = (ushort4*)(dst + off.v[s]);
        if (isf32) {
            const float4* src = (const float4*)pt.p[s];
            for (int i = tid0; i < n4; i += stride) {
                float4 f = src[i];
                ushort4 u;
                u.x = f2us(f.x); u.y = f2us(f.y); u.z = f2us(f.z); u.w = f2us(f.w);
                d4[i] = u;
            }
        } else {
            const ushort4* src = (const ushort4*)pt.p[s];
            for (int i = tid0; i < n4; i += stride) d4[i] = src[i];
        }
    }
    for (int i = tid0; i < N_PTS; i += stride) {
        float x, y, z;
        if (isf32) {
            const float* c = (const float*)pt.p[1];
            x = c[i * 3 + 0]; y = c[i * 3 + 1]; z = c[i * 3 + 2];
        } else {
            const bf16* c = (const bf16*)pt.p[1];
            x = bf2f(c[i * 3 + 0]); y = bf2f(c[i * 3 + 1]); z = bf2f(c[i * 3 + 2]);
        }
        coordf4[i] = make_float4(x, y, z, 0.f);
    }
}

// ---- moments: 9 pos moments, shadowed atomics ----
__global__ __launch_bounds__(256) void moments_kernel(
    const float4* __restrict__ coordf4, const int* __restrict__ knn, double* __restrict__ stM)
{
    float a[9];
    #pragma unroll
    for (int i = 0; i < 9; ++i) a[i] = 0.f;
    const int stride = gridDim.x * 256;
    const int nq = N_ROWS / 4;
    for (int r4 = blockIdx.x * 256 + threadIdx.x; r4 < nq; r4 += stride) {
        const int4 jj = ((const int4*)knn)[r4];
        const float4 c0 = coordf4[r4 >> 2];
        const int ja[4] = { jj.x, jj.y, jj.z, jj.w };
        #pragma unroll
        for (int rr = 0; rr < 4; ++rr) {
            const int j = ja[rr];
            const float mk = (j >= 0) ? 1.f : 0.f;
            const float4 cj = coordf4[j < 0 ? 0 : j];
            const float px = (cj.x - c0.x) * mk;
            const float py = (cj.y - c0.y) * mk;
            const float pz = (cj.z - c0.z) * mk;
            a[0] += px; a[1] += py; a[2] += pz;
            a[3] += px * px; a[4] += py * py; a[5] += pz * pz;
            a[6] += px * py; a[7] += px * pz; a[8] += py * pz;
        }
    }
    #pragma unroll
    for (int i = 0; i < 9; ++i)
        #pragma unroll
        for (int m = 32; m >= 1; m >>= 1) a[i] += __shfl_xor(a[i], m, 64);
    __shared__ float redm[4][9];
    const int lane = threadIdx.x & 63, wv = threadIdx.x >> 6;
    if (lane == 0)
        #pragma unroll
        for (int i = 0; i < 9; ++i) redm[wv][i] = a[i];
    __syncthreads();
    if (threadIdx.x < 9)
        atomicAdd(&stM[(blockIdx.x & (NSH - 1)) * 16 + threadIdx.x],
                  (double)(redm[0][threadIdx.x] + redm[1][threadIdx.x] +
                           redm[2][threadIdx.x] + redm[3][threadIdx.x]));
}

__device__ __forceinline__ void pb_bn_coef(
    const double* stMf, float invR, float w0, float w1, float w2, float bb,
    float gg, float be, float& sc, float& sh)
{
    const double ir = (double)invR;
    const float m1x = (float)(stMf[0] * ir), m1y = (float)(stMf[1] * ir), m1z = (float)(stMf[2] * ir);
    const float sxx = (float)(stMf[3] * ir), syy = (float)(stMf[4] * ir), szz = (float)(stMf[5] * ir);
    const float sxy = (float)(stMf[6] * ir), sxz = (float)(stMf[7] * ir), syz = (float)(stMf[8] * ir);
    const float dot = w0 * m1x + w1 * m1y + w2 * m1z;
    const float mu = dot + bb;
    const float eu2 = w0 * w0 * sxx + w1 * w1 * syy + w2 * w2 * szz
                    + 2.f * (w0 * w1 * sxy + w0 * w2 * sxz + w1 * w2 * syz)
                    + 2.f * bb * dot + bb * bb;
    const float va = eu2 - mu * mu;
    sc = gg * rsqrtf(va + EPS);
    sh = be - mu * sc;
}

// ---- prep: W_pe/b_pe both depths + fold stM ----
__global__ __launch_bounds__(256) void prep_kernel(
    const bf16* __restrict__ pb2w, const bf16* __restrict__ pb2b,
    const bf16* __restrict__ we1w, const bf16* __restrict__ we1b,
    const double* __restrict__ stM, double* __restrict__ stMf, float* __restrict__ W_peB)
{
    const int t = threadIdx.x;
    const int k = t >> 2, g = t & 3;
    for (int d = 0; d < 2; ++d) {
        const bf16* w2 = pb2w + d * 4096;
        const bf16* we1 = we1w + d * 256;
        float s = 0.f;
        for (int j = 0; j < 64; ++j) s += bf2f(w2[k * 64 + j]) * bf2f(we1[j * 4 + g]);
        W_peB[d * 288 + k * 4 + g] = s;
        if (t < 4) {
            float sb = 0.f;
            for (int j = 0; j < 64; ++j) sb += bf2f(pb2b[d * 64 + j]) * bf2f(we1[j * 4 + t]);
            W_peB[d * 288 + 256 + t] = sb + bf2f(we1b[d * 4 + t]);
        }
    }
    if (t < 9) {
        double s = 0.0;
        for (int sh = 0; sh < NSH; ++sh) s += stM[sh * 16 + t];
        stMf[t] = s;
    }
}

// ---- mfma_gemm: out[p][c] = f(in)[p][:] @ W[:,c] (+bias), up to 3 weight phases ----
__global__ __launch_bounds__(256) void mfma_gemm_kernel(
    const bf16* __restrict__ inB,
    const double* __restrict__ in_st, const bf16* __restrict__ in_g, const bf16* __restrict__ in_b,
    float in_inv,
    const bf16* __restrict__ resId, bf16* __restrict__ xOut,
    int nph,
    const bf16* __restrict__ W0, const bf16* __restrict__ B0, bf16* __restrict__ O0, double* __restrict__ S0,
    const bf16* __restrict__ W1, const bf16* __restrict__ B1, bf16* __restrict__ O1, double* __restrict__ S1,
    const bf16* __restrict__ W2, const bf16* __restrict__ B2, bf16* __restrict__ O2, double* __restrict__ S2,
    int n)
{
    __shared__ unsigned short in_l[64][72];      // [p][k] bf16, pad 72
    __shared__ unsigned short wt_l[3][64][72];   // [c][k] = W^T bf16
    __shared__ float sc_l[64], sh_l[64];
    __shared__ float redS[4][64], redS2[4][64];
    const int t = threadIdx.x;
    const int wv = t >> 6, lane = t & 63;
    const int ln = lane & 15, quad = lane >> 4;

    if (in_st && t < 64) {
        double s1 = 0.0, s2 = 0.0;
        #pragma unroll
        for (int sh = 0; sh < NSH; ++sh) { s1 += in_st[sh * 128 + t]; s2 += in_st[sh * 128 + 64 + t]; }
        float m = (float)(s1 * (double)in_inv);
        float va = (float)(s2 * (double)in_inv) - m * m;
        float sc = bf2f(in_g[t]) * rsqrtf(va + EPS);
        sc_l[t] = sc; sh_l[t] = bf2f(in_b[t]) - m * sc;
    }
    const bf16* Ws[3] = { W0, W1, W2 };
    for (int ph = 0; ph < nph; ++ph) {
        #pragma unroll
        for (int i = 0; i < 4; ++i) {
            int e = i * 1024 + t * 4;
            int k = e >> 6, c = e & 63;
            ushort4 u = *(const ushort4*)(Ws[ph] + e);
            wt_l[ph][c + 0][k] = u.x; wt_l[ph][c + 1][k] = u.y;
            wt_l[ph][c + 2][k] = u.z; wt_l[ph][c + 3][k] = u.w;
        }
    }
    __syncthreads();
    const int base = blockIdx.x * 64;
    #pragma unroll
    for (int i = 0; i < 4; ++i) {
        int e = i * 1024 + t * 4;
        int p = e >> 6, k = e & 63;
        float v[4] = { 0.f, 0.f, 0.f, 0.f };
        if (base + p < n) {
            ushort4 u = *(const ushort4*)(inB + (size_t)(base + p) * 64 + k);
            v[0] = us2f(u.x); v[1] = us2f(u.y); v[2] = us2f(u.z); v[3] = us2f(u.w);
            if (in_st) {
                #pragma unroll
                for (int j = 0; j < 4; ++j) v[j] = v[j] * sc_l[k + j] + sh_l[k + j];
            }
            if (resId) {
                ushort4 r = *(const ushort4*)(resId + (size_t)(base + p) * 64 + k);
                v[0] += us2f(r.x); v[1] += us2f(r.y); v[2] += us2f(r.z); v[3] += us2f(r.w);
            }
            if (in_st) {
                #pragma unroll
                for (int j = 0; j < 4; ++j) v[j] = fmaxf(v[j], 0.f);
            }
        }
        ushort4 o;
        o.x = f2us(v[0]); o.y = f2us(v[1]); o.z = f2us(v[2]); o.w = f2us(v[3]);
        *(ushort4*)&in_l[p][k] = o;
        if (xOut && base + p < n) *(ushort4*)(xOut + (size_t)(base + p) * 64 + k) = o;
    }
    __syncthreads();

    const short8 a0 = *(const short8*)&in_l[wv * 16 + ln][quad * 8];
    const short8 a1 = *(const short8*)&in_l[wv * 16 + ln][32 + quad * 8];

    for (int ph = 0; ph < nph; ++ph) {
        const bf16* Bp = (ph == 0) ? B0 : (ph == 1) ? B1 : B2;
        bf16* Op = (ph == 0) ? O0 : (ph == 1) ? O1 : O2;
        double* Sp = (ph == 0) ? S0 : (ph == 1) ? S1 : S2;
        float ls[4] = { 0.f, 0.f, 0.f, 0.f }, ls2[4] = { 0.f, 0.f, 0.f, 0.f };
        #pragma unroll
        for (int tl = 0; tl < 4; ++tl) {
            f32x4 acc = { 0.f, 0.f, 0.f, 0.f };
            const short8 b0 = *(const short8*)&wt_l[ph][tl * 16 + ln][quad * 8];
            const short8 b1 = *(const short8*)&wt_l[ph][tl * 16 + ln][32 + quad * 8];
            acc = __builtin_amdgcn_mfma_f32_16x16x32_bf16(a0, b0, acc, 0, 0, 0);
            acc = __builtin_amdgcn_mfma_f32_16x16x32_bf16(a1, b1, acc, 0, 0, 0);
            const float bias = Bp ? bf2f(Bp[tl * 16 + ln]) : 0.f;
            #pragma unroll
            for (int r = 0; r < 4; ++r) {
                const int p = base + wv * 16 + quad * 4 + r;
                if (p < n) {
                    float val = acc[r] + bias;
                    Op[(size_t)p * 64 + tl * 16 + ln] = f2bf(val);
                    ls[tl] += val; ls2[tl] += val * val;
                }
            }
        }
        if (Sp) {
            #pragma unroll
            for (int tl = 0; tl < 4; ++tl) {
                ls[tl] += __shfl_xor(ls[tl], 16, 64);  ls[tl] += __shfl_xor(ls[tl], 32, 64);
                ls2[tl] += __shfl_xor(ls2[tl], 16, 64); ls2[tl] += __shfl_xor(ls2[tl], 32, 64);
            }
            if (quad == 0) {
                #pragma unroll
                for (int tl = 0; tl < 4; ++tl) {
                    redS[wv][tl * 16 + ln] = ls[tl];
                    redS2[wv][tl * 16 + ln] = ls2[tl];
                }
            }
            __syncthreads();
            if (t < 64) {
                float s = redS[0][t] + redS[1][t] + redS[2][t] + redS[3][t];
                float s2 = redS2[0][t] + redS2[1][t] + redS2[2][t] + redS2[3][t];
                double* st = Sp + (blockIdx.x & (NSH - 1)) * 128;
                atomicAdd(&st[t], (double)s);
                atomicAdd(&st[64 + t], (double)s2);
            }
            __syncthreads();
        }
    }
}

// ---- qkw1: qw1 = relu(bn(q))@we1, kw1 = relu(bn(k))@we1 ----
__global__ __launch_bounds__(256) void qkw1_kernel(
    const bf16* __restrict__ qp, const bf16* __restrict__ kp,
    const double* __restrict__ stQ, const double* __restrict__ stK,
    const bf16* __restrict__ q_g, const bf16* __restrict__ q_be,
    const bf16* __restrict__ k_g, const bf16* __restrict__ k_be,
    const bf16* __restrict__ we1w,
    float* __restrict__ qw1, float* __restrict__ kw1, int n, float invN)
{
    __shared__ float q_l[64][65];
    __shared__ float k_l[64][65];
    __shared__ float scq[64], shq[64], sck[64], shk[64];
    __shared__ float w1[64][4];
    const int t = threadIdx.x;
    if (t < 64) {
        double s1 = 0.0, s2 = 0.0;
        #pragma unroll
        for (int sh = 0; sh < NSH; ++sh) { s1 += stQ[sh * 128 + t]; s2 += stQ[sh * 128 + 64 + t]; }
        float m = (float)(s1 * (double)invN);
        float va = (float)(s2 * (double)invN) - m * m;
        float sc = bf2f(q_g[t]) * rsqrtf(va + EPS);
        scq[t] = sc; shq[t] = bf2f(q_be[t]) - m * sc;
        s1 = 0.0; s2 = 0.0;
        #pragma unroll
        for (int sh = 0; sh < NSH; ++sh) { s1 += stK[sh * 128 + t]; s2 += stK[sh * 128 + 64 + t]; }
        m = (float)(s1 * (double)invN);
        va = (float)(s2 * (double)invN) - m * m;
        sc = bf2f(k_g[t]) * rsqrtf(va + EPS);
        sck[t] = sc; shk[t] = bf2f(k_be[t]) - m * sc;
    }
    w1[t >> 2][t & 3] = bf2f(we1w[t]);
    const int base = blockIdx.x * 64;
    #pragma unroll
    for (int i = 0; i < 4; ++i) {
        int e = i * 1024 + t * 4;
        int p = e >> 6, k = e & 63;
        float qv[4] = {0.f, 0.f, 0.f, 0.f}, kv[4] = {0.f, 0.f, 0.f, 0.f};
        if (base + p < n) {
            ushort4 uq = *(const ushort4*)(qp + (size_t)(base + p) * 64 + k);
            ushort4 uk = *(const ushort4*)(kp + (size_t)(base + p) * 64 + k);
            qv[0] = us2f(uq.x); qv[1] = us2f(uq.y); qv[2] = us2f(uq.z); qv[3] = us2f(uq.w);
            kv[0] = us2f(uk.x); kv[1] = us2f(uk.y); kv[2] = us2f(uk.z); kv[3] = us2f(uk.w);
        }
        #pragma unroll
        for (int j = 0; j < 4; ++j) { q_l[p][k + j] = qv[j]; k_l[p][k + j] = kv[j]; }
    }
    __syncthreads();
    const int p = t & 63, g = t >> 6;
    float sq = 0.f, sk = 0.f;
    #pragma unroll
    for (int k = 0; k < 64; ++k) {
        float qv = fmaxf(q_l[p][k] * scq[k] + shq[k], 0.f);
        float kv = fmaxf(k_l[p][k] * sck[k] + shk[k], 0.f);
        sq += qv * w1[k][g];
        sk += kv * w1[k][g];
    }
    const int pp = base + p;
    if (pp < n) { qw1[pp * 4 + g] = sq; kw1[pp * 4 + g] = sk; }
}

// ---- wp: wp = mask*kw1[idx] - qw1[n] + t@W_pe + b_pe ; shadowed stats ----
__global__ __launch_bounds__(256) void wp_kernel(
    const float4* __restrict__ coordf4, const int* __restrict__ knn,
    const bf16* __restrict__ pb1w, const bf16* __restrict__ pb1b,
    const double* __restrict__ stMf, const bf16* __restrict__ pb_g, const bf16* __restrict__ pb_be,
    const float* __restrict__ W_pe, const float* __restrict__ b_pe,
    const float4* __restrict__ qw1, const float4* __restrict__ kw1,
    float4* __restrict__ wp, double* __restrict__ stWE, float invR)
{
    __shared__ float4 cfA[64];
    __shared__ float4 cfW[64];
    __shared__ float bpe_l[4];
    const int t = threadIdx.x;
    if (t < 64) {
        float w0 = bf2f(pb1w[t]), w1 = bf2f(pb1w[64 + t]), w2 = bf2f(pb1w[128 + t]), bb = bf2f(pb1b[t]);
        float sc, sh;
        pb_bn_coef(stMf, invR, w0, w1, w2, bb, bf2f(pb_g[t]), bf2f(pb_be[t]), sc, sh);
        cfA[t] = make_float4(w0 * sc, w1 * sc, w2 * sc, bb * sc + sh);
        cfW[t] = make_float4(W_pe[t * 4 + 0], W_pe[t * 4 + 1], W_pe[t * 4 + 2], W_pe[t * 4 + 3]);
    }
    if (t < 4) bpe_l[t] = b_pe[t];
    __syncthreads();

    float sg[4] = {0.f, 0.f, 0.f, 0.f}, q2[4] = {0.f, 0.f, 0.f, 0.f};
    const int rbase = blockIdx.x * 1024 + t * 4;
    if (rbase < N_ROWS) {
        const int4 jj = *(const int4*)(knn + rbase);
        const int nn = rbase >> 4;
        const float4 c0 = coordf4[nn];
        float px[4], py[4], pz[4], mk[4];
        int js[4];
        const int jarr[4] = { jj.x, jj.y, jj.z, jj.w };
        #pragma unroll
        for (int rr = 0; rr < 4; ++rr) {
            const int j = jarr[rr];
            mk[rr] = (j >= 0) ? 1.f : 0.f;
            js[rr] = j < 0 ? 0 : j;
            const float4 cj = coordf4[js[rr]];
            px[rr] = (cj.x - c0.x) * mk[rr];
            py[rr] = (cj.y - c0.y) * mk[rr];
            pz[rr] = (cj.z - c0.z) * mk[rr];
        }
        float pa[4][4];
        #pragma unroll
        for (int rr = 0; rr < 4; ++rr)
            #pragma unroll
            for (int g = 0; g < 4; ++g) pa[rr][g] = 0.f;
        #pragma unroll 4
        for (int c = 0; c < 64; ++c) {
            const float4 A = cfA[c];
            const float4 Wv = cfW[c];
            #pragma unroll
            for (int rr = 0; rr < 4; ++rr) {
                const float tt = fmaxf(px[rr] * A.x + py[rr] * A.y + pz[rr] * A.z + A.w, 0.f);
                pa[rr][0] += tt * Wv.x; pa[rr][1] += tt * Wv.y;
                pa[rr][2] += tt * Wv.z; pa[rr][3] += tt * Wv.w;
            }
        }
        const float4 qv = qw1[nn];
        #pragma unroll
        for (int rr = 0; rr < 4; ++rr) {
            const float4 kv = kw1[js[rr]];
            float4 val;
            val.x = mk[rr] * kv.x - qv.x + pa[rr][0] + bpe_l[0];
            val.y = mk[rr] * kv.y - qv.y + pa[rr][1] + bpe_l[1];
            val.z = mk[rr] * kv.z - qv.z + pa[rr][2] + bpe_l[2];
            val.w = mk[rr] * kv.w - qv.w + pa[rr][3] + bpe_l[3];
            wp[rbase + rr] = val;
            sg[0] += val.x; sg[1] += val.y; sg[2] += val.z; sg[3] += val.w;
            q2[0] += val.x * val.x; q2[1] += val.y * val.y;
            q2[2] += val.z * val.z; q2[3] += val.w * val.w;
        }
    }
    float a8[8] = { sg[0], sg[1], sg[2], sg[3], q2[0], q2[1], q2[2], q2[3] };
    #pragma unroll
    for (int i = 0; i < 8; ++i)
        #pragma unroll
        for (int m = 32; m >= 1; m >>= 1) a8[i] += __shfl_xor(a8[i], m, 64);
    __shared__ float redw[4][8];
    const int lane = t & 63, wv = t >> 6;
    if (lane == 0)
        #pragma unroll
        for (int i = 0; i < 8; ++i) redw[wv][i] = a8[i];
    __syncthreads();
    if (t < 8)
        atomicAdd(&stWE[(blockIdx.x & (NSH - 1)) * 8 + t],
                  (double)(redw[0][t] + redw[1][t] + redw[2][t] + redw[3][t]));
}

// ---- attn: wave-independent, NO fences (same-wave LDS ops execute in order) ----
__global__ __launch_bounds__(256) void attn_kernel(
    const float4* __restrict__ coordf4, const int* __restrict__ knn,
    const bf16* __restrict__ pb1w, const bf16* __restrict__ pb1b,
    const double* __restrict__ stMf, const bf16* __restrict__ pb_g, const bf16* __restrict__ pb_be,
    const double* __restrict__ stWEsh, const bf16* __restrict__ we_g, const bf16* __restrict__ we_be,
    const bf16* __restrict__ we2w, const bf16* __restrict__ we2b,
    const bf16* __restrict__ pb2w, const bf16* __restrict__ pb2b,
    const float4* __restrict__ wp4, const bf16* __restrict__ v,
    bf16* __restrict__ a_out, double* __restrict__ stN2sh, float invR)
{
    __shared__ float pb2_l[64][64];
    __shared__ unsigned short t_l[4][16][64];   // wave-private
    __shared__ float tg_l[4][64][4];            // wave-private
    __shared__ float sWE[8];
    __shared__ float redS[4][64], redS2[4][64];
    const int t = threadIdx.x, c = t & 63, wv = t >> 6, g = c >> 4, sl = c & 15;
    #pragma unroll
    for (int i = 0; i < 4; ++i) {
        int e = i * 1024 + t * 4;
        ushort4 u = *(const ushort4*)(pb2w + e);
        int r = e >> 6, cc = e & 63;
        pb2_l[r][cc + 0] = us2f(u.x); pb2_l[r][cc + 1] = us2f(u.y);
        pb2_l[r][cc + 2] = us2f(u.z); pb2_l[r][cc + 3] = us2f(u.w);
    }
    if (t < 8) {
        double s = 0.0;
        #pragma unroll
        for (int sh = 0; sh < NSH; ++sh) s += stWEsh[sh * 8 + t];
        sWE[t] = (float)(s * (double)invR);
    }
    float A0, A1, A2, A3;
    {
        const float w0 = bf2f(pb1w[c]), w1 = bf2f(pb1w[64 + c]), w2 = bf2f(pb1w[128 + c]), bb = bf2f(pb1b[c]);
        float sc, sh;
        pb_bn_coef(stMf, invR, w0, w1, w2, bb, bf2f(pb_g[c]), bf2f(pb_be[c]), sc, sh);
        A0 = w0 * sc; A1 = w1 * sc; A2 = w2 * sc; A3 = bb * sc + sh;
    }
    __syncthreads();   // only for pb2_l / sWE staging
    float scW[4], shW[4], w2wv[4];
    #pragma unroll
    for (int gg = 0; gg < 4; ++gg) {
        float m = sWE[gg];
        float va = sWE[4 + gg] - m * m;
        float sc = bf2f(we_g[gg]) * rsqrtf(va + EPS);
        scW[gg] = sc; shW[gg] = bf2f(we_be[gg]) - m * sc;
        w2wv[gg] = bf2f(we2w[gg * 4 + g]);
    }
    const float w2bg = bf2f(we2b[g]);
    const float pb2bc = bf2f(pb2b[c]);
    float sa = 0.f, sa2 = 0.f;
    for (int p = blockIdx.x * 4 + wv; p < N_PTS; p += gridDim.x * 4) {
        float wgt[16];
        int jreg[16];
        // lane sl computes its group's logit for neighbor sl
        float4 q4 = wp4[p * 16 + sl];
        float r0 = fmaxf(q4.x * scW[0] + shW[0], 0.f);
        float r1 = fmaxf(q4.y * scW[1] + shW[1], 0.f);
        float r2 = fmaxf(q4.z * scW[2] + shW[2], 0.f);
        float r3 = fmaxf(q4.w * scW[3] + shW[3], 0.f);
        float val = r0 * w2wv[0] + r1 * w2wv[1] + r2 * w2wv[2] + r3 * w2wv[3] + w2bg;
        const int j = knn[p * 16 + sl];
        const float mkl = (j >= 0) ? 1.f : 0.f;
        const int jsl = j < 0 ? 0 : j;
        float mx = val;
        #pragma unroll
        for (int m2 = 1; m2 < 16; m2 <<= 1) mx = fmaxf(mx, __shfl_xor(mx, m2, 64));
        float e = __expf(val - mx);
        float ss = e;
        #pragma unroll
        for (int m2 = 1; m2 < 16; m2 <<= 1) ss += __shfl_xor(ss, m2, 64);
        const float wl = e * mkl / ss;
        #pragma unroll
        for (int s = 0; s < 16; ++s) {
            wgt[s] = __shfl(wl, (g << 4) | s, 64);
            jreg[s] = __shfl(jsl, (g << 4) | s, 64);
        }
        // hoist v-gathers: issue early so latency overlaps the LDS/t work below
        float vv[16];
        #pragma unroll
        for (int s = 0; s < 16; ++s) vv[s] = bf2f(v[(size_t)jreg[s] * 64 + c]);
        const float4 cc4 = coordf4[p];
        #pragma unroll
        for (int s = 0; s < 16; ++s) {
            const float4 cj = coordf4[jreg[s]];
            const float tt = fmaxf((cj.x - cc4.x) * A0 + (cj.y - cc4.y) * A1 +
                                   (cj.z - cc4.z) * A2 + A3, 0.f);
            t_l[wv][s][c] = f2us(tt);
        }
        // same-wave ds ops execute in program order: no fence needed (t_l is wave-private)
        {
            const int kb = c & 15;
            #pragma unroll
            for (int m2 = 0; m2 < 4; ++m2) {
                const int k = kb + 16 * m2;
                float s2 = 0.f;
                #pragma unroll
                for (int s = 0; s < 16; ++s) s2 += wgt[s] * us2f(t_l[wv][s][k]);
                tg_l[wv][k][g] = s2;
            }
        }
        {
            float Wg = 0.f;
            #pragma unroll
            for (int s = 0; s < 16; ++s) Wg += wgt[s];
            float vs = 0.f;
            #pragma unroll
            for (int s = 0; s < 16; ++s) vs += wgt[s] * vv[s];
            float acc = vs + pb2bc * Wg;
            #pragma unroll
            for (int k = 0; k < 64; ++k) acc += tg_l[wv][k][g] * pb2_l[k][c];
            a_out[(size_t)p * 64 + c] = f2bf(acc);
            sa += acc; sa2 += acc * acc;
        }
    }
    redS[wv][c] = sa; redS2[wv][c] = sa2;
    __syncthreads();
    double* st = stN2sh + (blockIdx.x & (NSH - 1)) * 128;
    if (t < 64) atomicAdd(&st[t], (double)(redS[0][t] + redS[1][t] + redS[2][t] + redS[3][t]));
    else if (t < 128) {
        int cc = t - 64;
        atomicAdd(&st[64 + cc], (double)(redS2[0][cc] + redS2[1][cc] + redS2[2][cc] + redS2[3][cc]));
    }
}

// ---- residual (final): out = relu(id + bn3(t3)), dual-dtype ----
__global__ __launch_bounds__(256) void residual_kernel(
    const bf16* __restrict__ t3, const double* __restrict__ stN3sh,
    const bf16* __restrict__ n3_g, const bf16* __restrict__ n3_b,
    const bf16* __restrict__ id, bf16* __restrict__ outB, float* __restrict__ outF,
    const int* __restrict__ flag, float invN)
{
    __shared__ float sc_l[64], sh_l[64];
    const int t = threadIdx.x;
    if (t < 64) {
        double s1 = 0.0, s2 = 0.0;
        #pragma unroll
        for (int sh = 0; sh < NSH; ++sh) { s1 += stN3sh[sh * 128 + t]; s2 += stN3sh[sh * 128 + 64 + t]; }
        float m = (float)(s1 * (double)invN);
        float va = (float)(s2 * (double)invN) - m * m;
        float sc = bf2f(n3_g[t]) * rsqrtf(va + EPS);
        sc_l[t] = sc; sh_l[t] = bf2f(n3_b[t]) - m * sc;
    }
    __syncthreads();
    const bool f32o = (*flag != 0);
    const size_t total = (size_t)N_PTS * 64;
    size_t base = (size_t)blockIdx.x * 4096 + (size_t)t * 16;
    #pragma unroll
    for (int j = 0; j < 4; ++j) {
        size_t e = base + (size_t)j * 4;
        if (e < total) {
            ushort4 t4 = *(const ushort4*)(t3 + e);
            ushort4 i4 = *(const ushort4*)(id + e);
            const int c0 = (int)(e & 63);
            float v0 = fmaxf(us2f(i4.x) + us2f(t4.x) * sc_l[c0 + 0] + sh_l[c0 + 0], 0.f);
            float v1 = fmaxf(us2f(i4.y) + us2f(t4.y) * sc_l[c0 + 1] + sh_l[c0 + 1], 0.f);
            float v2 = fmaxf(us2f(i4.z) + us2f(t4.z) * sc_l[c0 + 2] + sh_l[c0 + 2], 0.f);
            float v3 = fmaxf(us2f(i4.w) + us2f(t4.w) * sc_l[c0 + 3] + sh_l[c0 + 3], 0.f);
            if (f32o) *(float4*)(outF + e) = make_float4(v0, v1, v2, v3);
            else {
                ushort4 u;
                u.x = f2us(v0); u.y = f2us(v1); u.z = f2us(v2); u.w = f2us(v3);
                *(ushort4*)(outB + e) = u;
            }
        }
    }
}

extern "C" void kernel_launch(void* const* d_in, const int* in_sizes, int n_in,
                              void* d_out, int out_size, void* d_ws, size_t ws_size,
                              hipStream_t stream)
{
    const int* knn = (const int*)d_in[32];

    double* S = (double*)d_ws;
    double* stM  = S;                 // [16][16]
    double* stMf = S + 256;           // 16 (9 used)
    const int DBASE = 272, DSTR = 10368;
    const int TOTAL_ST = DBASE + 2 * DSTR;   // 21008 doubles
    int* flag = (int*)((char*)d_ws + TOTAL_ST * 8);

    float* fb    = (float*)((char*)d_ws + 172032);
    float* W_peB = fb;                        // 2*288
    float* qw1   = fb + 576;                  // N*4
    float* kw1   = qw1 + N_PTS * 4;
    float* cof4  = kw1 + N_PTS * 4;           // N float4
    float* t1f   = cof4 + N_PTS * 4;          // N_ROWS float4 region (wp); head aliased as t1 bf16
    bf16* t1b = (bf16*)t1f;
    bf16* qb  = (bf16*)(t1f + (size_t)N_ROWS * 4);
    bf16* kb  = qb + (size_t)N_PTS * 64;
    bf16* vb  = kb + (size_t)N_PTS * 64;
    bf16* xbb = vb + (size_t)N_PTS * 64;
    bf16* canon = xbb + (size_t)N_PTS * 64;

    PtrTable pt; IntTable sz, off;
    int acc = 0;
    bf16* ci[32];
    for (int i = 0; i < 32; ++i) {
        pt.p[i] = d_in[i];
        sz.v[i] = in_sizes[i];
        off.v[i] = acc;
        ci[i] = canon + acc;
        acc += in_sizes[i];
    }
    const bf16* feat  = ci[0];
    const bf16* fc1_w = ci[2];
    const bf16* q_w  = ci[3];  const bf16* q_b  = ci[4];  const bf16* q_g  = ci[5];  const bf16* q_be = ci[6];
    const bf16* k_w  = ci[7];  const bf16* k_b  = ci[8];  const bf16* k_g  = ci[9];  const bf16* k_be = ci[10];
    const bf16* v_w  = ci[11]; const bf16* v_b  = ci[12];
    const bf16* pb1_w = ci[13]; const bf16* pb1_b = ci[14]; const bf16* pb_g = ci[15]; const bf16* pb_be = ci[16];
    const bf16* pb2_w = ci[17]; const bf16* pb2_b = ci[18];
    const bf16* we1_w = ci[19]; const bf16* we1_b = ci[20]; const bf16* we_g = ci[21]; const bf16* we_be = ci[22];
    const bf16* we2_w = ci[23]; const bf16* we2_b = ci[24];
    const bf16* fc3_w = ci[25];
    const bf16* n1_g = ci[26]; const bf16* n1_b = ci[27];
    const bf16* n2_g = ci[28]; const bf16* n2_b = ci[29];
    const bf16* n3_g = ci[30]; const bf16* n3_b = ci[31];

    const int GG = (N_PTS + 63) / 64;       // 782
    const int GR = (N_ROWS + 1023) / 1024;  // 782
    const float invN = 1.f / (float)N_PTS;
    const float invR = 1.f / (float)N_ROWS;

    sniff_kernel<<<1, 256, 0, stream>>>(d_in[0], flag);
    canon_kernel<<<512, 256, 0, stream>>>(flag, pt, sz, off, canon, (float4*)cof4);
    hipMemsetAsync(S, 0, (size_t)TOTAL_ST * 8, stream);
    moments_kernel<<<512, 256, 0, stream>>>((const float4*)cof4, knn, stM);
    prep_kernel<<<1, 256, 0, stream>>>(pb2_w, pb2_b, we1_w, we1_b, stM, stMf, W_peB);

    for (int d = 0; d < 2; ++d) {
        double* D0 = S + DBASE + d * DSTR;
        double* st1  = D0;
        double* stQ  = D0 + 2048;
        double* stK  = D0 + 4096;
        double* stN2 = D0 + 6144;
        double* stN3 = D0 + 8192;
        double* stWE = D0 + 10240;
        double* stN3prev = S + DBASE + 0 * DSTR + 8192;

        if (d == 0)
            mfma_gemm_kernel<<<GG, 256, 0, stream>>>(feat, nullptr, nullptr, nullptr, 0.f,
                nullptr, nullptr, 1,
                fc1_w, nullptr, t1b, st1,
                nullptr, nullptr, nullptr, nullptr,
                nullptr, nullptr, nullptr, nullptr, N_PTS);
        else
            mfma_gemm_kernel<<<GG, 256, 0, stream>>>(kb, stN3prev, n3_g, n3_b, invN,
                feat, xbb, 1,
                fc1_w + 4096, nullptr, t1b, st1,
                nullptr, nullptr, nullptr, nullptr,
                nullptr, nullptr, nullptr, nullptr, N_PTS);
        mfma_gemm_kernel<<<GG, 256, 0, stream>>>(t1b, st1, n1_g + d * 64, n1_b + d * 64, invN,
            nullptr, nullptr, 3,
            q_w + d * 4096, q_b + d * 64, qb, stQ,
            k_w + d * 4096, k_b + d * 64, kb, stK,
            v_w + d * 4096, v_b + d * 64, vb, nullptr, N_PTS);
        qkw1_kernel<<<GG, 256, 0, stream>>>(qb, kb, stQ, stK, q_g + d * 64, q_be + d * 64,
                                            k_g + d * 64, k_be + d * 64,
                                            we1_w + d * 256, qw1, kw1, N_PTS, invN);
        wp_kernel<<<GR, 256, 0, stream>>>((const float4*)cof4, knn, pb1_w + d * 192, pb1_b + d * 64,
                                          stMf, pb_g + d * 64, pb_be + d * 64,
                                          W_peB + d * 288, W_peB + d * 288 + 256,
                                          (const float4*)qw1, (const float4*)kw1,
                                          (float4*)t1f, stWE, invR);
        attn_kernel<<<2560, 256, 0, stream>>>((const float4*)cof4, knn, pb1_w + d * 192, pb1_b + d * 64,
                                              stMf, pb_g + d * 64, pb_be + d * 64,
                                              stWE, we_g + d * 4, we_be + d * 4,
                                              we2_w + d * 16, we2_b + d * 4,
                                              pb2_w + d * 4096, pb2_b + d * 64,
                                              (const float4*)t1f, vb, qb, stN2, invR);
        mfma_gemm_kernel<<<GG, 256, 0, stream>>>(qb, stN2, n2_g + d * 64, n2_b + d * 64, invN,
            nullptr, nullptr, 1,
            fc3_w + d * 4096, nullptr, kb, stN3,
            nullptr, nullptr, nullptr, nullptr,
            nullptr, nullptr, nullptr, nullptr, N_PTS);
    }
    residual_kernel<<<GG, 256, 0, stream>>>(kb, S + DBASE + DSTR + 8192,
                                            n3_g + 64, n3_b + 64,
                                            xbb, (bf16*)d_out, (float*)d_out, flag, invN);
}

// Round 8
// 489.652 us; speedup vs baseline: 1.4995x; 1.4995x over previous
//
#include <hip/hip_runtime.h>
#include <hip/hip_bf16.h>

typedef __hip_bfloat16 bf16;
typedef __attribute__((ext_vector_type(8))) short short8;
typedef __attribute__((ext_vector_type(4))) float f32x4;

#define N_PTS 50000
#define N_ROWS (N_PTS * 16)
#define EPS 1e-5f
#define NSH 16   // stat shadow copies

__device__ __forceinline__ float bf2f(bf16 x) { return __bfloat162float(x); }
__device__ __forceinline__ bf16 f2bf(float x) { return __float2bfloat16(x); }
__device__ __forceinline__ float us2f(unsigned short u) {
    union { unsigned int i; float f; } c; c.i = ((unsigned int)u) << 16; return c.f;
}
__device__ __forceinline__ unsigned short f2us(float x) {
    bf16 b = __float2bfloat16(x); return *reinterpret_cast<unsigned short*>(&b);
}

struct PtrTable { const void* p[32]; };
struct IntTable { int v[32]; };

// ---- sniff: f32 (flag=1) vs bf16 (flag=0) ----
__global__ __launch_bounds__(256) void sniff_kernel(const void* feat, int* flag)
{
    __shared__ int cnt;
    if (threadIdx.x == 0) cnt = 0;
    __syncthreads();
    const unsigned short* u = (const unsigned short*)feat;
    int local = 0;
    #pragma unroll
    for (int j = 0; j < 8; ++j) {
        unsigned short bits = u[2 * (threadIdx.x * 8 + j)];
        int e = (bits >> 7) & 0xFF;
        if (e >= 140) local++;
    }
    atomicAdd(&cnt, local);
    __syncthreads();
    if (threadIdx.x == 0) *flag = (cnt > 16) ? 1 : 0;
}

// ---- canon: vectorized copy to canonical bf16 + coordf4 ----
__global__ __launch_bounds__(256) void canon_kernel(
    const int* __restrict__ flag, PtrTable pt, IntTable sz, IntTable off,
    bf16* __restrict__ dst, float4* __restrict__ coordf4)
{
    const bool isf32 = (*flag != 0);
    const int stride = gridDim.x * blockDim.x;
    const int tid0 = blockIdx.x * blockDim.x + threadIdx.x;
    for (int s = 0; s < 32; ++s) {
        const int n4 = sz.v[s] >> 2;
        ushort4* d4 = (ushort4*)(dst + off.v[s]);
        if (isf32) {
            const float4* src = (const float4*)pt.p[s];
            for (int i = tid0; i < n4; i += stride) {
                float4 f = src[i];
                ushort4 u;
                u.x = f2us(f.x); u.y = f2us(f.y); u.z = f2us(f.z); u.w = f2us(f.w);
                d4[i] = u;
            }
        } else {
            const ushort4* src = (const ushort4*)pt.p[s];
            for (int i = tid0; i < n4; i += stride) d4[i] = src[i];
        }
    }
    for (int i = tid0; i < N_PTS; i += stride) {
        float x, y, z;
        if (isf32) {
            const float* c = (const float*)pt.p[1];
            x = c[i * 3 + 0]; y = c[i * 3 + 1]; z = c[i * 3 + 2];
        } else {
            const bf16* c = (const bf16*)pt.p[1];
            x = bf2f(c[i * 3 + 0]); y = bf2f(c[i * 3 + 1]); z = bf2f(c[i * 3 + 2]);
        }
        coordf4[i] = make_float4(x, y, z, 0.f);
    }
}

// ---- moments: 9 pos moments, shadowed atomics ----
__global__ __launch_bounds__(256) void moments_kernel(
    const float4* __restrict__ coordf4, const int* __restrict__ knn, double* __restrict__ stM)
{
    float a[9];
    #pragma unroll
    for (int i = 0; i < 9; ++i) a[i] = 0.f;
    const int stride = gridDim.x * 256;
    const int nq = N_ROWS / 4;
    for (int r4 = blockIdx.x * 256 + threadIdx.x; r4 < nq; r4 += stride) {
        const int4 jj = ((const int4*)knn)[r4];
        const float4 c0 = coordf4[r4 >> 2];
        const int ja[4] = { jj.x, jj.y, jj.z, jj.w };
        #pragma unroll
        for (int rr = 0; rr < 4; ++rr) {
            const int j = ja[rr];
            const float mk = (j >= 0) ? 1.f : 0.f;
            const float4 cj = coordf4[j < 0 ? 0 : j];
            const float px = (cj.x - c0.x) * mk;
            const float py = (cj.y - c0.y) * mk;
            const float pz = (cj.z - c0.z) * mk;
            a[0] += px; a[1] += py; a[2] += pz;
            a[3] += px * px; a[4] += py * py; a[5] += pz * pz;
            a[6] += px * py; a[7] += px * pz; a[8] += py * pz;
        }
    }
    #pragma unroll
    for (int i = 0; i < 9; ++i)
        #pragma unroll
        for (int m = 32; m >= 1; m >>= 1) a[i] += __shfl_xor(a[i], m, 64);
    __shared__ float redm[4][9];
    const int lane = threadIdx.x & 63, wv = threadIdx.x >> 6;
    if (lane == 0)
        #pragma unroll
        for (int i = 0; i < 9; ++i) redm[wv][i] = a[i];
    __syncthreads();
    if (threadIdx.x < 9)
        atomicAdd(&stM[(blockIdx.x & (NSH - 1)) * 16 + threadIdx.x],
                  (double)(redm[0][threadIdx.x] + redm[1][threadIdx.x] +
                           redm[2][threadIdx.x] + redm[3][threadIdx.x]));
}

__device__ __forceinline__ void pb_bn_coef(
    const double* stMf, float invR, float w0, float w1, float w2, float bb,
    float gg, float be, float& sc, float& sh)
{
    const double ir = (double)invR;
    const float m1x = (float)(stMf[0] * ir), m1y = (float)(stMf[1] * ir), m1z = (float)(stMf[2] * ir);
    const float sxx = (float)(stMf[3] * ir), syy = (float)(stMf[4] * ir), szz = (float)(stMf[5] * ir);
    const float sxy = (float)(stMf[6] * ir), sxz = (float)(stMf[7] * ir), syz = (float)(stMf[8] * ir);
    const float dot = w0 * m1x + w1 * m1y + w2 * m1z;
    const float mu = dot + bb;
    const float eu2 = w0 * w0 * sxx + w1 * w1 * syy + w2 * w2 * szz
                    + 2.f * (w0 * w1 * sxy + w0 * w2 * sxz + w1 * w2 * syz)
                    + 2.f * bb * dot + bb * bb;
    const float va = eu2 - mu * mu;
    sc = gg * rsqrtf(va + EPS);
    sh = be - mu * sc;
}

// ---- prep: W_pe/b_pe both depths + fold stM ----
__global__ __launch_bounds__(256) void prep_kernel(
    const bf16* __restrict__ pb2w, const bf16* __restrict__ pb2b,
    const bf16* __restrict__ we1w, const bf16* __restrict__ we1b,
    const double* __restrict__ stM, double* __restrict__ stMf, float* __restrict__ W_peB)
{
    const int t = threadIdx.x;
    const int k = t >> 2, g = t & 3;
    for (int d = 0; d < 2; ++d) {
        const bf16* w2 = pb2w + d * 4096;
        const bf16* we1 = we1w + d * 256;
        float s = 0.f;
        for (int j = 0; j < 64; ++j) s += bf2f(w2[k * 64 + j]) * bf2f(we1[j * 4 + g]);
        W_peB[d * 288 + k * 4 + g] = s;
        if (t < 4) {
            float sb = 0.f;
            for (int j = 0; j < 64; ++j) sb += bf2f(pb2b[d * 64 + j]) * bf2f(we1[j * 4 + t]);
            W_peB[d * 288 + 256 + t] = sb + bf2f(we1b[d * 4 + t]);
        }
    }
    if (t < 9) {
        double s = 0.0;
        for (int sh = 0; sh < NSH; ++sh) s += stM[sh * 16 + t];
        stMf[t] = s;
    }
}

// ---- mfma_gemm: out[p][c] = f(in)[p][:] @ W[:,c] (+bias), up to 3 weight phases ----
__global__ __launch_bounds__(256) void mfma_gemm_kernel(
    const bf16* __restrict__ inB,
    const double* __restrict__ in_st, const bf16* __restrict__ in_g, const bf16* __restrict__ in_b,
    float in_inv,
    const bf16* __restrict__ resId, bf16* __restrict__ xOut,
    int nph,
    const bf16* __restrict__ W0, const bf16* __restrict__ B0, bf16* __restrict__ O0, double* __restrict__ S0,
    const bf16* __restrict__ W1, const bf16* __restrict__ B1, bf16* __restrict__ O1, double* __restrict__ S1,
    const bf16* __restrict__ W2, const bf16* __restrict__ B2, bf16* __restrict__ O2, double* __restrict__ S2,
    int n)
{
    __shared__ unsigned short in_l[64][72];      // [p][k] bf16, pad 72
    __shared__ unsigned short wt_l[3][64][72];   // [c][k] = W^T bf16
    __shared__ float sc_l[64], sh_l[64];
    __shared__ float redS[4][64], redS2[4][64];
    const int t = threadIdx.x;
    const int wv = t >> 6, lane = t & 63;
    const int ln = lane & 15, quad = lane >> 4;

    if (in_st && t < 64) {
        double s1 = 0.0, s2 = 0.0;
        #pragma unroll
        for (int sh = 0; sh < NSH; ++sh) { s1 += in_st[sh * 128 + t]; s2 += in_st[sh * 128 + 64 + t]; }
        float m = (float)(s1 * (double)in_inv);
        float va = (float)(s2 * (double)in_inv) - m * m;
        float sc = bf2f(in_g[t]) * rsqrtf(va + EPS);
        sc_l[t] = sc; sh_l[t] = bf2f(in_b[t]) - m * sc;
    }
    const bf16* Ws[3] = { W0, W1, W2 };
    for (int ph = 0; ph < nph; ++ph) {
        #pragma unroll
        for (int i = 0; i < 4; ++i) {
            int e = i * 1024 + t * 4;
            int k = e >> 6, c = e & 63;
            ushort4 u = *(const ushort4*)(Ws[ph] + e);
            wt_l[ph][c + 0][k] = u.x; wt_l[ph][c + 1][k] = u.y;
            wt_l[ph][c + 2][k] = u.z; wt_l[ph][c + 3][k] = u.w;
        }
    }
    __syncthreads();
    const int base = blockIdx.x * 64;
    #pragma unroll
    for (int i = 0; i < 4; ++i) {
        int e = i * 1024 + t * 4;
        int p = e >> 6, k = e & 63;
        float v[4] = { 0.f, 0.f, 0.f, 0.f };
        if (base + p < n) {
            ushort4 u = *(const ushort4*)(inB + (size_t)(base + p) * 64 + k);
            v[0] = us2f(u.x); v[1] = us2f(u.y); v[2] = us2f(u.z); v[3] = us2f(u.w);
            if (in_st) {
                #pragma unroll
                for (int j = 0; j < 4; ++j) v[j] = v[j] * sc_l[k + j] + sh_l[k + j];
            }
            if (resId) {
                ushort4 r = *(const ushort4*)(resId + (size_t)(base + p) * 64 + k);
                v[0] += us2f(r.x); v[1] += us2f(r.y); v[2] += us2f(r.z); v[3] += us2f(r.w);
            }
            if (in_st) {
                #pragma unroll
                for (int j = 0; j < 4; ++j) v[j] = fmaxf(v[j], 0.f);
            }
        }
        ushort4 o;
        o.x = f2us(v[0]); o.y = f2us(v[1]); o.z = f2us(v[2]); o.w = f2us(v[3]);
        *(ushort4*)&in_l[p][k] = o;
        if (xOut && base + p < n) *(ushort4*)(xOut + (size_t)(base + p) * 64 + k) = o;
    }
    __syncthreads();

    const short8 a0 = *(const short8*)&in_l[wv * 16 + ln][quad * 8];
    const short8 a1 = *(const short8*)&in_l[wv * 16 + ln][32 + quad * 8];

    for (int ph = 0; ph < nph; ++ph) {
        const bf16* Bp = (ph == 0) ? B0 : (ph == 1) ? B1 : B2;
        bf16* Op = (ph == 0) ? O0 : (ph == 1) ? O1 : O2;
        double* Sp = (ph == 0) ? S0 : (ph == 1) ? S1 : S2;
        float ls[4] = { 0.f, 0.f, 0.f, 0.f }, ls2[4] = { 0.f, 0.f, 0.f, 0.f };
        #pragma unroll
        for (int tl = 0; tl < 4; ++tl) {
            f32x4 acc = { 0.f, 0.f, 0.f, 0.f };
            const short8 b0 = *(const short8*)&wt_l[ph][tl * 16 + ln][quad * 8];
            const short8 b1 = *(const short8*)&wt_l[ph][tl * 16 + ln][32 + quad * 8];
            acc = __builtin_amdgcn_mfma_f32_16x16x32_bf16(a0, b0, acc, 0, 0, 0);
            acc = __builtin_amdgcn_mfma_f32_16x16x32_bf16(a1, b1, acc, 0, 0, 0);
            const float bias = Bp ? bf2f(Bp[tl * 16 + ln]) : 0.f;
            #pragma unroll
            for (int r = 0; r < 4; ++r) {
                const int p = base + wv * 16 + quad * 4 + r;
                if (p < n) {
                    float val = acc[r] + bias;
                    Op[(size_t)p * 64 + tl * 16 + ln] = f2bf(val);
                    ls[tl] += val; ls2[tl] += val * val;
                }
            }
        }
        if (Sp) {
            #pragma unroll
            for (int tl = 0; tl < 4; ++tl) {
                ls[tl] += __shfl_xor(ls[tl], 16, 64);  ls[tl] += __shfl_xor(ls[tl], 32, 64);
                ls2[tl] += __shfl_xor(ls2[tl], 16, 64); ls2[tl] += __shfl_xor(ls2[tl], 32, 64);
            }
            if (quad == 0) {
                #pragma unroll
                for (int tl = 0; tl < 4; ++tl) {
                    redS[wv][tl * 16 + ln] = ls[tl];
                    redS2[wv][tl * 16 + ln] = ls2[tl];
                }
            }
            __syncthreads();
            if (t < 64) {
                float s = redS[0][t] + redS[1][t] + redS[2][t] + redS[3][t];
                float s2 = redS2[0][t] + redS2[1][t] + redS2[2][t] + redS2[3][t];
                double* st = Sp + (blockIdx.x & (NSH - 1)) * 128;
                atomicAdd(&st[t], (double)s);
                atomicAdd(&st[64 + t], (double)s2);
            }
            __syncthreads();
        }
    }
}

// ---- qkw1: qw1 = relu(bn(q))@we1, kw1 = relu(bn(k))@we1 ----
__global__ __launch_bounds__(256) void qkw1_kernel(
    const bf16* __restrict__ qp, const bf16* __restrict__ kp,
    const double* __restrict__ stQ, const double* __restrict__ stK,
    const bf16* __restrict__ q_g, const bf16* __restrict__ q_be,
    const bf16* __restrict__ k_g, const bf16* __restrict__ k_be,
    const bf16* __restrict__ we1w,
    float* __restrict__ qw1, float* __restrict__ kw1, int n, float invN)
{
    __shared__ float q_l[64][65];
    __shared__ float k_l[64][65];
    __shared__ float scq[64], shq[64], sck[64], shk[64];
    __shared__ float w1[64][4];
    const int t = threadIdx.x;
    if (t < 64) {
        double s1 = 0.0, s2 = 0.0;
        #pragma unroll
        for (int sh = 0; sh < NSH; ++sh) { s1 += stQ[sh * 128 + t]; s2 += stQ[sh * 128 + 64 + t]; }
        float m = (float)(s1 * (double)invN);
        float va = (float)(s2 * (double)invN) - m * m;
        float sc = bf2f(q_g[t]) * rsqrtf(va + EPS);
        scq[t] = sc; shq[t] = bf2f(q_be[t]) - m * sc;
        s1 = 0.0; s2 = 0.0;
        #pragma unroll
        for (int sh = 0; sh < NSH; ++sh) { s1 += stK[sh * 128 + t]; s2 += stK[sh * 128 + 64 + t]; }
        m = (float)(s1 * (double)invN);
        va = (float)(s2 * (double)invN) - m * m;
        sc = bf2f(k_g[t]) * rsqrtf(va + EPS);
        sck[t] = sc; shk[t] = bf2f(k_be[t]) - m * sc;
    }
    w1[t >> 2][t & 3] = bf2f(we1w[t]);
    const int base = blockIdx.x * 64;
    #pragma unroll
    for (int i = 0; i < 4; ++i) {
        int e = i * 1024 + t * 4;
        int p = e >> 6, k = e & 63;
        float qv[4] = {0.f, 0.f, 0.f, 0.f}, kv[4] = {0.f, 0.f, 0.f, 0.f};
        if (base + p < n) {
            ushort4 uq = *(const ushort4*)(qp + (size_t)(base + p) * 64 + k);
            ushort4 uk = *(const ushort4*)(kp + (size_t)(base + p) * 64 + k);
            qv[0] = us2f(uq.x); qv[1] = us2f(uq.y); qv[2] = us2f(uq.z); qv[3] = us2f(uq.w);
            kv[0] = us2f(uk.x); kv[1] = us2f(uk.y); kv[2] = us2f(uk.z); kv[3] = us2f(uk.w);
        }
        #pragma unroll
        for (int j = 0; j < 4; ++j) { q_l[p][k + j] = qv[j]; k_l[p][k + j] = kv[j]; }
    }
    __syncthreads();
    const int p = t & 63, g = t >> 6;
    float sq = 0.f, sk = 0.f;
    #pragma unroll
    for (int k = 0; k < 64; ++k) {
        float qv = fmaxf(q_l[p][k] * scq[k] + shq[k], 0.f);
        float kv = fmaxf(k_l[p][k] * sck[k] + shk[k], 0.f);
        sq += qv * w1[k][g];
        sk += kv * w1[k][g];
    }
    const int pp = base + p;
    if (pp < n) { qw1[pp * 4 + g] = sq; kw1[pp * 4 + g] = sk; }
}

// ---- wp: wp = mask*kw1[idx] - qw1[n] + t@W_pe + b_pe ; shadowed stats ----
__global__ __launch_bounds__(256) void wp_kernel(
    const float4* __restrict__ coordf4, const int* __restrict__ knn,
    const bf16* __restrict__ pb1w, const bf16* __restrict__ pb1b,
    const double* __restrict__ stMf, const bf16* __restrict__ pb_g, const bf16* __restrict__ pb_be,
    const float* __restrict__ W_pe, const float* __restrict__ b_pe,
    const float4* __restrict__ qw1, const float4* __restrict__ kw1,
    float4* __restrict__ wp, double* __restrict__ stWE, float invR)
{
    __shared__ float4 cfA[64];
    __shared__ float4 cfW[64];
    __shared__ float bpe_l[4];
    const int t = threadIdx.x;
    if (t < 64) {
        float w0 = bf2f(pb1w[t]), w1 = bf2f(pb1w[64 + t]), w2 = bf2f(pb1w[128 + t]), bb = bf2f(pb1b[t]);
        float sc, sh;
        pb_bn_coef(stMf, invR, w0, w1, w2, bb, bf2f(pb_g[t]), bf2f(pb_be[t]), sc, sh);
        cfA[t] = make_float4(w0 * sc, w1 * sc, w2 * sc, bb * sc + sh);
        cfW[t] = make_float4(W_pe[t * 4 + 0], W_pe[t * 4 + 1], W_pe[t * 4 + 2], W_pe[t * 4 + 3]);
    }
    if (t < 4) bpe_l[t] = b_pe[t];
    __syncthreads();

    float sg[4] = {0.f, 0.f, 0.f, 0.f}, q2[4] = {0.f, 0.f, 0.f, 0.f};
    const int rbase = blockIdx.x * 1024 + t * 4;
    if (rbase < N_ROWS) {
        const int4 jj = *(const int4*)(knn + rbase);
        const int nn = rbase >> 4;
        const float4 c0 = coordf4[nn];
        float px[4], py[4], pz[4], mk[4];
        int js[4];
        const int jarr[4] = { jj.x, jj.y, jj.z, jj.w };
        #pragma unroll
        for (int rr = 0; rr < 4; ++rr) {
            const int j = jarr[rr];
            mk[rr] = (j >= 0) ? 1.f : 0.f;
            js[rr] = j < 0 ? 0 : j;
            const float4 cj = coordf4[js[rr]];
            px[rr] = (cj.x - c0.x) * mk[rr];
            py[rr] = (cj.y - c0.y) * mk[rr];
            pz[rr] = (cj.z - c0.z) * mk[rr];
        }
        float pa[4][4];
        #pragma unroll
        for (int rr = 0; rr < 4; ++rr)
            #pragma unroll
            for (int g = 0; g < 4; ++g) pa[rr][g] = 0.f;
        #pragma unroll 4
        for (int c = 0; c < 64; ++c) {
            const float4 A = cfA[c];
            const float4 Wv = cfW[c];
            #pragma unroll
            for (int rr = 0; rr < 4; ++rr) {
                const float tt = fmaxf(px[rr] * A.x + py[rr] * A.y + pz[rr] * A.z + A.w, 0.f);
                pa[rr][0] += tt * Wv.x; pa[rr][1] += tt * Wv.y;
                pa[rr][2] += tt * Wv.z; pa[rr][3] += tt * Wv.w;
            }
        }
        const float4 qv = qw1[nn];
        #pragma unroll
        for (int rr = 0; rr < 4; ++rr) {
            const float4 kv = kw1[js[rr]];
            float4 val;
            val.x = mk[rr] * kv.x - qv.x + pa[rr][0] + bpe_l[0];
            val.y = mk[rr] * kv.y - qv.y + pa[rr][1] + bpe_l[1];
            val.z = mk[rr] * kv.z - qv.z + pa[rr][2] + bpe_l[2];
            val.w = mk[rr] * kv.w - qv.w + pa[rr][3] + bpe_l[3];
            wp[rbase + rr] = val;
            sg[0] += val.x; sg[1] += val.y; sg[2] += val.z; sg[3] += val.w;
            q2[0] += val.x * val.x; q2[1] += val.y * val.y;
            q2[2] += val.z * val.z; q2[3] += val.w * val.w;
        }
    }
    float a8[8] = { sg[0], sg[1], sg[2], sg[3], q2[0], q2[1], q2[2], q2[3] };
    #pragma unroll
    for (int i = 0; i < 8; ++i)
        #pragma unroll
        for (int m = 32; m >= 1; m >>= 1) a8[i] += __shfl_xor(a8[i], m, 64);
    __shared__ float redw[4][8];
    const int lane = t & 63, wv = t >> 6;
    if (lane == 0)
        #pragma unroll
        for (int i = 0; i < 8; ++i) redw[wv][i] = a8[i];
    __syncthreads();
    if (t < 8)
        atomicAdd(&stWE[(blockIdx.x & (NSH - 1)) * 8 + t],
                  (double)(redw[0][t] + redw[1][t] + redw[2][t] + redw[3][t]));
}

// ---- attn: round-5 structure (barriers, lane-coop softmax, Tg factorization) ----
__global__ __launch_bounds__(256) void attn_kernel(
    const float4* __restrict__ coordf4, const int* __restrict__ knn,
    const bf16* __restrict__ pb1w, const bf16* __restrict__ pb1b,
    const double* __restrict__ stMf, const bf16* __restrict__ pb_g, const bf16* __restrict__ pb_be,
    const double* __restrict__ stWEsh, const bf16* __restrict__ we_g, const bf16* __restrict__ we_be,
    const bf16* __restrict__ we2w, const bf16* __restrict__ we2b,
    const bf16* __restrict__ pb2w, const bf16* __restrict__ pb2b,
    const float4* __restrict__ wp4, const bf16* __restrict__ v,
    bf16* __restrict__ a_out, double* __restrict__ stN2sh, float invR)
{
    __shared__ float pb2_l[64][64];
    __shared__ unsigned short t_l[4][16][64];
    __shared__ float tg_l[4][64][4];
    __shared__ float sWE[8];
    __shared__ float redS[4][64], redS2[4][64];
    const int t = threadIdx.x, c = t & 63, wv = t >> 6, g = c >> 4, sl = c & 15;
    #pragma unroll
    for (int i = 0; i < 4; ++i) {
        int e = i * 1024 + t * 4;
        ushort4 u = *(const ushort4*)(pb2w + e);
        int r = e >> 6, cc = e & 63;
        pb2_l[r][cc + 0] = us2f(u.x); pb2_l[r][cc + 1] = us2f(u.y);
        pb2_l[r][cc + 2] = us2f(u.z); pb2_l[r][cc + 3] = us2f(u.w);
    }
    if (t < 8) {
        double s = 0.0;
        #pragma unroll
        for (int sh = 0; sh < NSH; ++sh) s += stWEsh[sh * 8 + t];
        sWE[t] = (float)(s * (double)invR);
    }
    float A0, A1, A2, A3;
    {
        const float w0 = bf2f(pb1w[c]), w1 = bf2f(pb1w[64 + c]), w2 = bf2f(pb1w[128 + c]), bb = bf2f(pb1b[c]);
        float sc, sh;
        pb_bn_coef(stMf, invR, w0, w1, w2, bb, bf2f(pb_g[c]), bf2f(pb_be[c]), sc, sh);
        A0 = w0 * sc; A1 = w1 * sc; A2 = w2 * sc; A3 = bb * sc + sh;
    }
    __syncthreads();
    float scW[4], shW[4], w2wv[4];
    #pragma unroll
    for (int gg = 0; gg < 4; ++gg) {
        float m = sWE[gg];
        float va = sWE[4 + gg] - m * m;
        float sc = bf2f(we_g[gg]) * rsqrtf(va + EPS);
        scW[gg] = sc; shW[gg] = bf2f(we_be[gg]) - m * sc;
        w2wv[gg] = bf2f(we2w[gg * 4 + g]);
    }
    const float w2bg = bf2f(we2b[g]);
    const float pb2bc = bf2f(pb2b[c]);
    float sa = 0.f, sa2 = 0.f;
    for (int pbase = blockIdx.x * 4; pbase < N_PTS; pbase += gridDim.x * 4) {
        const int p = pbase + wv;
        const bool act = p < N_PTS;
        float wgt[16];
        int jreg[16];
        if (act) {
            // lane sl computes its group's logit for neighbor sl
            float4 q4 = wp4[p * 16 + sl];
            float r0 = fmaxf(q4.x * scW[0] + shW[0], 0.f);
            float r1 = fmaxf(q4.y * scW[1] + shW[1], 0.f);
            float r2 = fmaxf(q4.z * scW[2] + shW[2], 0.f);
            float r3 = fmaxf(q4.w * scW[3] + shW[3], 0.f);
            float val = r0 * w2wv[0] + r1 * w2wv[1] + r2 * w2wv[2] + r3 * w2wv[3] + w2bg;
            const int j = knn[p * 16 + sl];
            const float mkl = (j >= 0) ? 1.f : 0.f;
            const int jsl = j < 0 ? 0 : j;
            float mx = val;
            #pragma unroll
            for (int m2 = 1; m2 < 16; m2 <<= 1) mx = fmaxf(mx, __shfl_xor(mx, m2, 64));
            float e = __expf(val - mx);
            float ss = e;
            #pragma unroll
            for (int m2 = 1; m2 < 16; m2 <<= 1) ss += __shfl_xor(ss, m2, 64);
            const float wl = e * mkl / ss;
            #pragma unroll
            for (int s = 0; s < 16; ++s) {
                wgt[s] = __shfl(wl, (g << 4) | s, 64);
                jreg[s] = __shfl(jsl, (g << 4) | s, 64);
            }
            const float4 cc4 = coordf4[p];
            #pragma unroll
            for (int s = 0; s < 16; ++s) {
                const float4 cj = coordf4[jreg[s]];
                const float tt = fmaxf((cj.x - cc4.x) * A0 + (cj.y - cc4.y) * A1 +
                                       (cj.z - cc4.z) * A2 + A3, 0.f);
                t_l[wv][s][c] = f2us(tt);
            }
        }
        __syncthreads();
        if (act) {
            const int kb = c & 15;
            #pragma unroll
            for (int m2 = 0; m2 < 4; ++m2) {
                const int k = kb + 16 * m2;
                float s2 = 0.f;
                #pragma unroll
                for (int s = 0; s < 16; ++s) s2 += wgt[s] * us2f(t_l[wv][s][k]);
                tg_l[wv][k][g] = s2;
            }
        }
        __syncthreads();
        if (act) {
            float Wg = 0.f;
            #pragma unroll
            for (int s = 0; s < 16; ++s) Wg += wgt[s];
            float vs = 0.f;
            #pragma unroll
            for (int s = 0; s < 16; ++s) vs += wgt[s] * bf2f(v[(size_t)jreg[s] * 64 + c]);
            float acc = vs + pb2bc * Wg;
            #pragma unroll
            for (int k = 0; k < 64; ++k) acc += tg_l[wv][k][g] * pb2_l[k][c];
            a_out[(size_t)p * 64 + c] = f2bf(acc);
            sa += acc; sa2 += acc * acc;
        }
    }
    redS[wv][c] = sa; redS2[wv][c] = sa2;
    __syncthreads();
    double* st = stN2sh + (blockIdx.x & (NSH - 1)) * 128;
    if (t < 64) atomicAdd(&st[t], (double)(redS[0][t] + redS[1][t] + redS[2][t] + redS[3][t]));
    else if (t < 128) {
        int cc = t - 64;
        atomicAdd(&st[64 + cc], (double)(redS2[0][cc] + redS2[1][cc] + redS2[2][cc] + redS2[3][cc]));
    }
}

// ---- residual (final): out = relu(id + bn3(t3)), dual-dtype ----
__global__ __launch_bounds__(256) void residual_kernel(
    const bf16* __restrict__ t3, const double* __restrict__ stN3sh,
    const bf16* __restrict__ n3_g, const bf16* __restrict__ n3_b,
    const bf16* __restrict__ id, bf16* __restrict__ outB, float* __restrict__ outF,
    const int* __restrict__ flag, float invN)
{
    __shared__ float sc_l[64], sh_l[64];
    const int t = threadIdx.x;
    if (t < 64) {
        double s1 = 0.0, s2 = 0.0;
        #pragma unroll
        for (int sh = 0; sh < NSH; ++sh) { s1 += stN3sh[sh * 128 + t]; s2 += stN3sh[sh * 128 + 64 + t]; }
        float m = (float)(s1 * (double)invN);
        float va = (float)(s2 * (double)invN) - m * m;
        float sc = bf2f(n3_g[t]) * rsqrtf(va + EPS);
        sc_l[t] = sc; sh_l[t] = bf2f(n3_b[t]) - m * sc;
    }
    __syncthreads();
    const bool f32o = (*flag != 0);
    const size_t total = (size_t)N_PTS * 64;
    size_t base = (size_t)blockIdx.x * 4096 + (size_t)t * 16;
    #pragma unroll
    for (int j = 0; j < 4; ++j) {
        size_t e = base + (size_t)j * 4;
        if (e < total) {
            ushort4 t4 = *(const ushort4*)(t3 + e);
            ushort4 i4 = *(const ushort4*)(id + e);
            const int c0 = (int)(e & 63);
            float v0 = fmaxf(us2f(i4.x) + us2f(t4.x) * sc_l[c0 + 0] + sh_l[c0 + 0], 0.f);
            float v1 = fmaxf(us2f(i4.y) + us2f(t4.y) * sc_l[c0 + 1] + sh_l[c0 + 1], 0.f);
            float v2 = fmaxf(us2f(i4.z) + us2f(t4.z) * sc_l[c0 + 2] + sh_l[c0 + 2], 0.f);
            float v3 = fmaxf(us2f(i4.w) + us2f(t4.w) * sc_l[c0 + 3] + sh_l[c0 + 3], 0.f);
            if (f32o) *(float4*)(outF + e) = make_float4(v0, v1, v2, v3);
            else {
                ushort4 u;
                u.x = f2us(v0); u.y = f2us(v1); u.z = f2us(v2); u.w = f2us(v3);
                *(ushort4*)(outB + e) = u;
            }
        }
    }
}

extern "C" void kernel_launch(void* const* d_in, const int* in_sizes, int n_in,
                              void* d_out, int out_size, void* d_ws, size_t ws_size,
                              hipStream_t stream)
{
    const int* knn = (const int*)d_in[32];

    double* S = (double*)d_ws;
    double* stM  = S;                 // [16][16]
    double* stMf = S + 256;           // 16 (9 used)
    const int DBASE = 272, DSTR = 10368;
    const int TOTAL_ST = DBASE + 2 * DSTR;   // 21008 doubles
    int* flag = (int*)((char*)d_ws + TOTAL_ST * 8);

    float* fb    = (float*)((char*)d_ws + 172032);
    float* W_peB = fb;                        // 2*288
    float* qw1   = fb + 576;                  // N*4
    float* kw1   = qw1 + N_PTS * 4;
    float* cof4  = kw1 + N_PTS * 4;           // N float4
    float* t1f   = cof4 + N_PTS * 4;          // N_ROWS float4 region (wp); head aliased as t1 bf16
    bf16* t1b = (bf16*)t1f;
    bf16* qb  = (bf16*)(t1f + (size_t)N_ROWS * 4);
    bf16* kb  = qb + (size_t)N_PTS * 64;
    bf16* vb  = kb + (size_t)N_PTS * 64;
    bf16* xbb = vb + (size_t)N_PTS * 64;
    bf16* canon = xbb + (size_t)N_PTS * 64;

    PtrTable pt; IntTable sz, off;
    int acc = 0;
    bf16* ci[32];
    for (int i = 0; i < 32; ++i) {
        pt.p[i] = d_in[i];
        sz.v[i] = in_sizes[i];
        off.v[i] = acc;
        ci[i] = canon + acc;
        acc += in_sizes[i];
    }
    const bf16* feat  = ci[0];
    const bf16* fc1_w = ci[2];
    const bf16* q_w  = ci[3];  const bf16* q_b  = ci[4];  const bf16* q_g  = ci[5];  const bf16* q_be = ci[6];
    const bf16* k_w  = ci[7];  const bf16* k_b  = ci[8];  const bf16* k_g  = ci[9];  const bf16* k_be = ci[10];
    const bf16* v_w  = ci[11]; const bf16* v_b  = ci[12];
    const bf16* pb1_w = ci[13]; const bf16* pb1_b = ci[14]; const bf16* pb_g = ci[15]; const bf16* pb_be = ci[16];
    const bf16* pb2_w = ci[17]; const bf16* pb2_b = ci[18];
    const bf16* we1_w = ci[19]; const bf16* we1_b = ci[20]; const bf16* we_g = ci[21]; const bf16* we_be = ci[22];
    const bf16* we2_w = ci[23]; const bf16* we2_b = ci[24];
    const bf16* fc3_w = ci[25];
    const bf16* n1_g = ci[26]; const bf16* n1_b = ci[27];
    const bf16* n2_g = ci[28]; const bf16* n2_b = ci[29];
    const bf16* n3_g = ci[30]; const bf16* n3_b = ci[31];

    const int GG = (N_PTS + 63) / 64;       // 782
    const int GR = (N_ROWS + 1023) / 1024;  // 782
    const float invN = 1.f / (float)N_PTS;
    const float invR = 1.f / (float)N_ROWS;

    sniff_kernel<<<1, 256, 0, stream>>>(d_in[0], flag);
    canon_kernel<<<512, 256, 0, stream>>>(flag, pt, sz, off, canon, (float4*)cof4);
    hipMemsetAsync(S, 0, (size_t)TOTAL_ST * 8, stream);
    moments_kernel<<<512, 256, 0, stream>>>((const float4*)cof4, knn, stM);
    prep_kernel<<<1, 256, 0, stream>>>(pb2_w, pb2_b, we1_w, we1_b, stM, stMf, W_peB);

    for (int d = 0; d < 2; ++d) {
        double* D0 = S + DBASE + d * DSTR;
        double* st1  = D0;
        double* stQ  = D0 + 2048;
        double* stK  = D0 + 4096;
        double* stN2 = D0 + 6144;
        double* stN3 = D0 + 8192;
        double* stWE = D0 + 10240;
        double* stN3prev = S + DBASE + 0 * DSTR + 8192;

        if (d == 0)
            mfma_gemm_kernel<<<GG, 256, 0, stream>>>(feat, nullptr, nullptr, nullptr, 0.f,
                nullptr, nullptr, 1,
                fc1_w, nullptr, t1b, st1,
                nullptr, nullptr, nullptr, nullptr,
                nullptr, nullptr, nullptr, nullptr, N_PTS);
        else
            mfma_gemm_kernel<<<GG, 256, 0, stream>>>(kb, stN3prev, n3_g, n3_b, invN,
                feat, xbb, 1,
                fc1_w + 4096, nullptr, t1b, st1,
                nullptr, nullptr, nullptr, nullptr,
                nullptr, nullptr, nullptr, nullptr, N_PTS);
        mfma_gemm_kernel<<<GG, 256, 0, stream>>>(t1b, st1, n1_g + d * 64, n1_b + d * 64, invN,
            nullptr, nullptr, 3,
            q_w + d * 4096, q_b + d * 64, qb, stQ,
            k_w + d * 4096, k_b + d * 64, kb, stK,
            v_w + d * 4096, v_b + d * 64, vb, nullptr, N_PTS);
        qkw1_kernel<<<GG, 256, 0, stream>>>(qb, kb, stQ, stK, q_g + d * 64, q_be + d * 64,
                                            k_g + d * 64, k_be + d * 64,
                                            we1_w + d * 256, qw1, kw1, N_PTS, invN);
        wp_kernel<<<GR, 256, 0, stream>>>((const float4*)cof4, knn, pb1_w + d * 192, pb1_b + d * 64,
                                          stMf, pb_g + d * 64, pb_be + d * 64,
                                          W_peB + d * 288, W_peB + d * 288 + 256,
                                          (const float4*)qw1, (const float4*)kw1,
                                          (float4*)t1f, stWE, invR);
        attn_kernel<<<2560, 256, 0, stream>>>((const float4*)cof4, knn, pb1_w + d * 192, pb1_b + d * 64,
                                              stMf, pb_g + d * 64, pb_be + d * 64,
                                              stWE, we_g + d * 4, we_be + d * 4,
                                              we2_w + d * 16, we2_b + d * 4,
                                              pb2_w + d * 4096, pb2_b + d * 64,
                                              (const float4*)t1f, vb, qb, stN2, invR);
        mfma_gemm_kernel<<<GG, 256, 0, stream>>>(qb, stN2, n2_g + d * 64, n2_b + d * 64, invN,
            nullptr, nullptr, 1,
            fc3_w + d * 4096, nullptr, kb, stN3,
            nullptr, nullptr, nullptr, nullptr,
            nullptr, nullptr, nullptr, nullptr, N_PTS);
    }
    residual_kernel<<<GG, 256, 0, stream>>>(kb, S + DBASE + DSTR + 8192,
                                            n3_g + 64, n3_b + 64,
                                            xbb, (bf16*)d_out, (float*)d_out, flag, invN);
}